// Round 5
// baseline (87.789 us; speedup 1.0000x reference)
//
#include <hip/hip_runtime.h>
#include <hip/hip_bf16.h>
#include <math.h>

#define BB 4
#define SS 4096
#define DD 64
#define KSPLIT 4      // pb k-splits
#define QSPLIT 8      // pa q-splits

typedef __attribute__((ext_vector_type(8))) short short8;
typedef __attribute__((ext_vector_type(4))) float f32x4;
typedef __attribute__((ext_vector_type(2))) unsigned int u32x2;
typedef unsigned int u32;
typedef unsigned short ushort_t;

#define MFMA16(a,b,c) __builtin_amdgcn_mfma_f32_16x16x32_bf16((a),(b),(c),0,0,0)
// exp(s/64) == exp2(s * C2SC)
#define C2SC 0.022542110700140054f

union Pk8 { short8 s8; u32 u[4]; u32x2 h[2]; };

static __device__ __forceinline__ unsigned short f2bf(float f) {
  union { float f; u32 u; } x; x.f = f;
  u32 r = (x.u + 0x7FFFu + ((x.u >> 16) & 1u)) >> 16;
  return (unsigned short)r;
}

static __device__ __forceinline__ u32 pk2(float a, float b) {
  return (u32)f2bf(a) | ((u32)f2bf(b) << 16);
}

static __device__ __forceinline__ void gload16(const void* g, void* l) {
  __builtin_amdgcn_global_load_lds((const __attribute__((address_space(1))) u32*)g,
                                   (__attribute__((address_space(3))) u32*)l, 16, 0, 0);
}

// ---------------- P0: convert Q,K -> bf16; zero out0 and z2
__global__ __launch_bounds__(256) void p0_convert(
    const float* __restrict__ q, const float* __restrict__ k,
    ushort_t* __restrict__ QB, ushort_t* __restrict__ KB,
    float* __restrict__ out0, float* __restrict__ z2)
{
  const size_t i = (size_t)blockIdx.x * 256 + threadIdx.x;  // over BB*SS*DD/4
  float4 a = ((const float4*)q)[i];
  float4 c = ((const float4*)k)[i];
  ((ushort4*)QB)[i] = make_ushort4(f2bf(a.x), f2bf(a.y), f2bf(a.z), f2bf(a.w));
  ((ushort4*)KB)[i] = make_ushort4(f2bf(c.x), f2bf(c.y), f2bf(c.z), f2bf(c.w));
  ((float4*)out0)[i] = make_float4(0.f, 0.f, 0.f, 0.f);
  if (blockIdx.x == 0) z2[threadIdx.x] = 0.f;
}

// ---------------- PA: Z[k] partial = sum_{q in chunk} exp(s_qk) via MFMA
// grid (SS/128, QSPLIT, BB), 256 thr. Wave w owns k rows 32w..32w+31 (K in regs).
__global__ __launch_bounds__(256, 4) void pa_colsum(
    const ushort_t* __restrict__ QB, const ushort_t* __restrict__ KB,
    float* __restrict__ Zp)
{
  const int kb0 = blockIdx.x * 128;
  const int qch = blockIdx.y;
  const int b   = blockIdx.z;
  const int t = threadIdx.x, w = t >> 6, lane = t & 63;
  const int g = lane >> 4, r15 = lane & 15;
  const int r8 = lane >> 3, c8 = lane & 7;
  const int QCH = SS / QSPLIT;         // 512
  const int NT = QCH / 64;             // 8

  __shared__ alignas(16) char qbuf[2][64*128];

  // K fragments in registers: 2 subtiles of 16 k-rows each
  short8 ak[2][2];
#pragma unroll
  for (int s = 0; s < 2; ++s)
#pragma unroll
    for (int dh = 0; dh < 2; ++dh)
      ak[s][dh] = *(const short8*)(KB + ((size_t)b*SS + kb0 + 32*w + 16*s + r15)*DD + 32*dh + 8*g);

  // prologue stage tile 0
  {
    const int q0 = qch * QCH;
#pragma unroll
    for (int j = 0; j < 2; ++j) {
      const int rl = 16*w + 8*j + r8;
      const char* gsrc = (const char*)(QB + ((size_t)b*SS + q0 + rl)*DD) + 16*(c8 ^ r8);
      gload16(gsrc, qbuf[0] + (16*w + 8*j)*128);
    }
  }
  asm volatile("s_waitcnt vmcnt(0)" ::: "memory");
  __syncthreads();

  float z[8];
#pragma unroll
  for (int i = 0; i < 8; ++i) z[i] = 0.f;

  int cur = 0;
  for (int tt = 0; tt < NT; ++tt) {
    if (tt < NT-1) {
      const int q0 = qch*QCH + (tt+1)*64;
#pragma unroll
      for (int j = 0; j < 2; ++j) {
        const int rl = 16*w + 8*j + r8;
        const char* gsrc = (const char*)(QB + ((size_t)b*SS + q0 + rl)*DD) + 16*(c8 ^ r8);
        gload16(gsrc, qbuf[cur^1] + (16*w + 8*j)*128);
      }
    }
    const char* qb = qbuf[cur];
#pragma unroll
    for (int qt = 0; qt < 4; ++qt) {
      const int qrow = 16*qt + r15;
      const char* base = qb + qrow*128;
      short8 bq0 = *(const short8*)(base + 16*((g    ) ^ (qrow & 7)));
      short8 bq1 = *(const short8*)(base + 16*((4 + g) ^ (qrow & 7)));
#pragma unroll
      for (int s = 0; s < 2; ++s) {
        f32x4 acc = {0.f,0.f,0.f,0.f};
        acc = MFMA16(ak[s][0], bq0, acc);
        acc = MFMA16(ak[s][1], bq1, acc);
        z[4*s+0] += exp2f(acc[0]*C2SC); z[4*s+1] += exp2f(acc[1]*C2SC);
        z[4*s+2] += exp2f(acc[2]*C2SC); z[4*s+3] += exp2f(acc[3]*C2SC);
      }
    }
    asm volatile("s_waitcnt vmcnt(0)" ::: "memory");
    __syncthreads();
    cur ^= 1;
  }
#pragma unroll
  for (int m = 1; m < 16; m <<= 1)
#pragma unroll
    for (int i = 0; i < 8; ++i) z[i] += __shfl_xor(z[i], m);
  if (r15 == 0) {
#pragma unroll
    for (int s = 0; s < 2; ++s)
#pragma unroll
      for (int r = 0; r < 4; ++r)
        Zp[((size_t)qch*BB + b)*SS + kb0 + 32*w + 16*s + 4*g + r] = z[4*s+r];
  }
}

// ---------------- P2: VT[b][d][s] = bf16( V[b][s][d] / Z[s] )
__global__ __launch_bounds__(256) void p2_vt(
    const float* __restrict__ v, const float* __restrict__ Zp,
    ushort_t* __restrict__ VT)
{
  const int k0 = blockIdx.x * 64;
  const int b  = blockIdx.y;
  const int t = threadIdx.x;
  __shared__ float vs[64][65];
  __shared__ float izs[64];
  {
    const int row = t >> 2, cq = (t & 3) * 16;
    const float* src = v + ((size_t)b*SS + k0 + row)*DD + cq;
#pragma unroll
    for (int i = 0; i < 4; ++i) {
      float4 x = ((const float4*)src)[i];
      vs[row][cq + 4*i + 0] = x.x; vs[row][cq + 4*i + 1] = x.y;
      vs[row][cq + 4*i + 2] = x.z; vs[row][cq + 4*i + 3] = x.w;
    }
  }
  if (t < 64) {
    float z = 0.f;
#pragma unroll
    for (int c = 0; c < QSPLIT; ++c)
      z += Zp[((size_t)c*BB + b)*SS + k0 + t];
    izs[t] = 1.0f / z;
  }
  __syncthreads();
  const int d = t >> 2, ks = (t & 3) * 16;
  u32* dst = (u32*)VT + (((size_t)b*DD + d)*SS + k0 + ks)/2;
#pragma unroll
  for (int i = 0; i < 8; ++i) {
    float a0 = vs[ks + 2*i    ][d] * izs[ks + 2*i    ];
    float a1 = vs[ks + 2*i + 1][d] * izs[ks + 2*i + 1];
    dst[i] = (u32)f2bf(a0) | ((u32)f2bf(a1) << 16);
  }
}

// ---------------- PB: attn += exp(QK^T/64) * VT over this block's k-quarter
// grid (SS/64, KSPLIT, BB), 256 thr. Wave w owns k-slice 16w (of each 128-k step);
// Q (64 rows) in registers; P stays in registers (QK^T C-frag == PV A-frag).
__global__ __launch_bounds__(256, 3) void pb_attn(
    const ushort_t* __restrict__ QB, const ushort_t* __restrict__ KB,
    const ushort_t* __restrict__ VT, float* __restrict__ out0)
{
  const int q0 = blockIdx.x * 64;
  const int kbase = blockIdx.y * (SS / KSPLIT);
  const int b  = blockIdx.z;
  const int t = threadIdx.x, w = t >> 6, lane = t & 63;
  const int g = lane >> 4, r15 = lane & 15;
  const int NT = SS / KSPLIT / 128;    // 8

  __shared__ alignas(16) char kbuf[128*128];   // 16 KB: K step tile
  __shared__ alignas(16) char vbuf[64*256];    // 16 KB: VT step tile

  // Q fragments in registers: all 64 q rows
  short8 aq[4][2];
#pragma unroll
  for (int qt = 0; qt < 4; ++qt)
#pragma unroll
    for (int dh = 0; dh < 2; ++dh)
      aq[qt][dh] = *(const short8*)(QB + ((size_t)b*SS + q0 + 16*qt + r15)*DD + 32*dh + 8*g);

  f32x4 acc[4][4];
#pragma unroll
  for (int qt = 0; qt < 4; ++qt)
#pragma unroll
    for (int dt = 0; dt < 4; ++dt) acc[qt][dt] = (f32x4){0.f,0.f,0.f,0.f};

  for (int kt = 0; kt < NT; ++kt) {
    const int k0 = kbase + kt*128;
    // stage K: 128 rows x 128B (chunk-xor swizzle over row&7)
#pragma unroll
    for (int j = 0; j < 4; ++j) {
      const int row = 32*j + 8*w + (lane >> 3);
      const char* gsrc = (const char*)(KB + ((size_t)b*SS + k0 + row)*DD) + 16*((lane & 7) ^ (row & 7));
      gload16(gsrc, kbuf + (32*j + 8*w)*128);
    }
    // stage VT: 64 rows x 256B (chunk-xor swizzle over row&15)
#pragma unroll
    for (int j = 0; j < 4; ++j) {
      const int row = 16*j + 4*w + (lane >> 4);
      const char* gsrc = (const char*)(VT + ((size_t)b*DD + row)*SS + k0) + 16*((lane & 15) ^ (row & 15));
      gload16(gsrc, vbuf + (16*j + 4*w)*256);
    }
    asm volatile("s_waitcnt vmcnt(0)" ::: "memory");
    __syncthreads();

    // QK^T (swapped: A=K, B=Q) for both 16-k subtiles; P packed in registers
    u32 pk[2][4][2];
#pragma unroll
    for (int s = 0; s < 2; ++s) {
      const int rowA = 64*s + 16*w + r15;
      const char* base = kbuf + rowA*128;
      short8 ka0 = *(const short8*)(base + 16*((g    ) ^ (rowA & 7)));
      short8 ka1 = *(const short8*)(base + 16*((4 + g) ^ (rowA & 7)));
#pragma unroll
      for (int qt = 0; qt < 4; ++qt) {
        f32x4 a = {0.f,0.f,0.f,0.f};
        a = MFMA16(ka0, aq[qt][0], a);
        a = MFMA16(ka1, aq[qt][1], a);
        pk[s][qt][0] = pk2(exp2f(a[0]*C2SC), exp2f(a[1]*C2SC));
        pk[s][qt][1] = pk2(exp2f(a[2]*C2SC), exp2f(a[3]*C2SC));
      }
    }
    // PV: A = P (registers), B = VT frags; kdim=32 pairs subtiles {s=0, s=1}
    Pk8 ap[4];
#pragma unroll
    for (int qt = 0; qt < 4; ++qt) {
      ap[qt].u[0] = pk[0][qt][0]; ap[qt].u[1] = pk[0][qt][1];
      ap[qt].u[2] = pk[1][qt][0]; ap[qt].u[3] = pk[1][qt][1];
    }
    const int cA = 2*w + (g >> 1);
    const int cB = 8 + 2*w + (g >> 1);
    const int sub8 = 8*(g & 1);
#pragma unroll
    for (int dt = 0; dt < 4; ++dt) {
      const int vrow = 16*dt + r15;
      Pk8 bv;
      bv.h[0] = *(const u32x2*)(vbuf + vrow*256 + 16*(cA ^ r15) + sub8);
      bv.h[1] = *(const u32x2*)(vbuf + vrow*256 + 16*(cB ^ r15) + sub8);
#pragma unroll
      for (int qt = 0; qt < 4; ++qt)
        acc[qt][dt] = MFMA16(ap[qt].s8, bv.s8, acc[qt][dt]);
    }
    __syncthreads();
  }

  // cross-wave reduction (2 rounds through 32KB LDS), then wave 0 atomics
  f32x4* r0 = (f32x4*)kbuf;
  f32x4* r1 = (f32x4*)vbuf;
  if (w == 1) {
#pragma unroll
    for (int qt = 0; qt < 4; ++qt)
#pragma unroll
      for (int dt = 0; dt < 4; ++dt) r0[(qt*4+dt)*64 + lane] = acc[qt][dt];
  }
  if (w == 2) {
#pragma unroll
    for (int qt = 0; qt < 4; ++qt)
#pragma unroll
      for (int dt = 0; dt < 4; ++dt) r1[(qt*4+dt)*64 + lane] = acc[qt][dt];
  }
  __syncthreads();
  if (w == 0) {
#pragma unroll
    for (int qt = 0; qt < 4; ++qt)
#pragma unroll
      for (int dt = 0; dt < 4; ++dt)
        acc[qt][dt] += r0[(qt*4+dt)*64 + lane] + r1[(qt*4+dt)*64 + lane];
  }
  __syncthreads();
  if (w == 3) {
#pragma unroll
    for (int qt = 0; qt < 4; ++qt)
#pragma unroll
      for (int dt = 0; dt < 4; ++dt) r0[(qt*4+dt)*64 + lane] = acc[qt][dt];
  }
  __syncthreads();
  if (w == 0) {
#pragma unroll
    for (int qt = 0; qt < 4; ++qt)
#pragma unroll
      for (int dt = 0; dt < 4; ++dt) {
        f32x4 s = acc[qt][dt] + r0[(qt*4+dt)*64 + lane];
#pragma unroll
        for (int rr = 0; rr < 4; ++rr)
          atomicAdd(&out0[((size_t)b*SS + q0 + 16*qt + 4*g + rr)*DD + 16*dt + r15], s[rr]);
      }
  }
}

// ---------------- K4F: column sum of exp(attn) over q -> z2 (atomic)
// grid (BB, SS/32), 256 thr.
__global__ __launch_bounds__(256) void k4f(
    const float* __restrict__ attn, float* __restrict__ z2)
{
  const int b = blockIdx.x;
  const int q0 = blockIdx.y * 32;
  const int t = threadIdx.x;
  const int d = t & 63, rg = t >> 6;
  float ze = 0.f;
#pragma unroll
  for (int i = 0; i < 8; ++i) {
    float a = attn[((size_t)b*SS + q0 + 4*i + rg)*DD + d];
    ze += __expf(a);
  }
  __shared__ float red[4][64];
  red[rg][d] = ze;
  __syncthreads();
  if (t < 64)
    atomicAdd(&z2[b*DD + t], red[0][t] + red[1][t] + red[2][t] + red[3][t]);
}

// ---------------- K6: attn_w = exp(attn) / z2
__global__ __launch_bounds__(256) void k6w(
    const float* __restrict__ attn, const float* __restrict__ z2,
    float* __restrict__ out1)
{
  const size_t i = (size_t)blockIdx.x * 256 + threadIdx.x;
  const int b = (int)(i >> 18);        // SS*DD = 262144
  const int d = (int)(i & 63);
  out1[i] = __expf(attn[i]) / z2[b*DD + d];
}

extern "C" void kernel_launch(void* const* d_in, const int* in_sizes, int n_in,
                              void* d_out, int out_size, void* d_ws, size_t ws_size,
                              hipStream_t stream) {
  const float* q = (const float*)d_in[0];
  const float* k = (const float*)d_in[1];
  const float* v = (const float*)d_in[2];
  float* out0 = (float*)d_out;
  float* out1 = out0 + (size_t)BB * SS * DD;

  // bf16 Q/K scratch lives in the out1 region (overwritten by k6w at the end).
  ushort_t* QB = (ushort_t*)out1;                 // 2 MB
  ushort_t* KB = QB + (size_t)BB * SS * DD;       // 2 MB

  float* ws = (float*)d_ws;
  ushort_t* VT = (ushort_t*)ws;                              // 2 MB bf16
  float* Zp = (float*)(VT + (size_t)BB * DD * SS);           // QSPLIT*BB*SS
  float* z2 = Zp + (size_t)QSPLIT * BB * SS;                 // BB*DD

  hipLaunchKernelGGL(p0_convert, dim3(BB*SS*DD/4/256), dim3(256), 0, stream, q, k, QB, KB, out0, z2);
  hipLaunchKernelGGL(pa_colsum, dim3(SS/128, QSPLIT, BB), dim3(256), 0, stream, QB, KB, Zp);
  hipLaunchKernelGGL(p2_vt, dim3(SS/64, BB), dim3(256), 0, stream, v, Zp, VT);
  hipLaunchKernelGGL(pb_attn, dim3(SS/64, KSPLIT, BB), dim3(256), 0, stream, QB, KB, VT, out0);
  hipLaunchKernelGGL(k4f, dim3(BB, SS/32), dim3(256), 0, stream, out0, z2);
  hipLaunchKernelGGL(k6w, dim3(BB*SS*DD/256), dim3(256), 0, stream, out0, z2, out1);
}